// Round 8
// baseline (890.505 us; speedup 1.0000x reference)
//
#include <hip/hip_runtime.h>
#include <math.h>

#define CC 21
#define HH 512
#define WW 512
#define HWN (HH*WW)
#define CHW (CC*HWN)
#define RAD 7
#define KS 15
#define NITER 5
#define NBKT 16

#define TW 128
#define TH 16
#define TWH (TW + 2*RAD)   // 142
#define LSTR 145           // odd LDS row stride

#define FEXP(x) __expf(x)
#define FLOG(x) __logf(x)
#define FRCP(x) __builtin_amdgcn_rcpf(x)

// ---------------------------------------------------------------------------
// init: M1t/M2t, diag extracts + flag, taps, zero sums (all parallel)
// ---------------------------------------------------------------------------
__global__ void k_init_small(const float* __restrict__ cm,
                             const float* __restrict__ skw,
                             const float* __restrict__ bkw,
                             float* __restrict__ M1t, float* __restrict__ M2t,
                             float* __restrict__ d1, float* __restrict__ d2,
                             int* __restrict__ dflag,
                             float* __restrict__ kbuf,
                             float* __restrict__ sums) {
    __shared__ int sbad;
    int t = threadIdx.x;
    if (t == 0) sbad = 0;
    __syncthreads();
    if (t < CC*CC) {
        int k = t / CC, c = t % CC;
        float a = 0.f, b = 0.f;
        for (int m = 0; m < CC; ++m) {
            a += cm[c*CC+m] * skw[m*CC+k];
            b += cm[c*CC+m] * bkw[m*CC+k];
        }
        M1t[t] = a; M2t[t] = b;
        if (k != c && (a != 0.f || b != 0.f)) atomicOr(&sbad, 1);
        if (k == c) { d1[c] = a; d2[c] = b; }
    }
    for (int i = t; i < NITER*NBKT*64; i += blockDim.x) sums[i] = 0.f;
    if (t == CC*CC) {
        float w3[KS], w10[KS];
        float s3 = 0.f, s10 = 0.f;
        for (int i = 0; i < KS; ++i) {
            float x = (float)(i - RAD);
            w3[i]  = expf(-0.5f * (x/3.0f)  * (x/3.0f));
            w10[i] = expf(-0.5f * (x/10.0f) * (x/10.0f));
            s3 += w3[i]; s10 += w10[i];
        }
        for (int i = 0; i < KS; ++i) {
            kbuf[i]      = w3[i]  / s3;
            kbuf[KS + i] = w10[i] / s10;
        }
    }
    __syncthreads();
    if (t == 0) dflag[0] = sbad ? 0 : 1;
}

// ---------------------------------------------------------------------------
// guide, spmT, sm0 = softmax(un), clique sums for iter 0.  (q0 == un)
// ---------------------------------------------------------------------------
__global__ void k_init_maps(const float* __restrict__ rgb,
                            const int* __restrict__ spin,
                            const float* __restrict__ un,
                            float* __restrict__ guide,
                            int* __restrict__ spmT,
                            float* __restrict__ sm,
                            const int* __restrict__ spidx,
                            float* __restrict__ sums0) {
    int p = blockIdx.x * blockDim.x + threadIdx.x;
    int h = p / WW, w = p - h*WW;
    float r = rgb[p*3+0] * (1.0f/255.0f);
    float g = rgb[p*3+1] * (1.0f/255.0f);
    float b = rgb[p*3+2] * (1.0f/255.0f);
    guide[p] = FEXP(-0.5f * (r*r + g*g + b*b) / 9.0f);   // theta_beta^2 = 9
    int s = spin[w*HH + h];
    spmT[p] = s;
    float v[CC];
    #pragma unroll
    for (int c = 0; c < CC; ++c) v[c] = un[p*CC + c];
    float mx = v[0];
    #pragma unroll
    for (int c = 1; c < CC; ++c) mx = fmaxf(mx, v[c]);
    float e[CC], ssum = 0.f;
    #pragma unroll
    for (int c = 0; c < CC; ++c) { e[c] = FEXP(v[c] - mx); ssum += e[c]; }
    float inv = FRCP(ssum);
    #pragma unroll
    for (int c = 0; c < CC; ++c) sm[c*HWN + p] = e[c] * inv;

    int sidx = spidx[0];
    bool c1 = (s == sidx), c2 = (s == sidx + 1);
    if (c1 || c2) {
        float* bkt = sums0 + (blockIdx.x & (NBKT-1)) * 64;
        float emx = FEXP(mx);
        if (c1) {
            #pragma unroll
            for (int c = 0; c < CC; ++c) {
                float ev = e[c] * emx;                       // exp(q)
                atomicAdd(&bkt[c], ev - 1.0f);
                float ea = (v[c] == mx) ? emx : ev * emx;    // exp(A_np)
                atomicAdd(&bkt[CC + c], ea - 1.0f);
            }
        } else {
            #pragma unroll
            for (int c = 0; c < CC; ++c) atomicAdd(&bkt[2*CC + c], e[c] * emx - 1.0f);
        }
    }
}

// ---------------------------------------------------------------------------
// fused separable blur. tile 128x16. v-pass: 284 units (142 cols x 2 row
// halves) over all 256 threads, register sliding window. h-pass: oy=t&15,
// xs=(t>>4)*8 (2-way banks only). VGPR fits 64 -> 8 waves/SIMD.
// ---------------------------------------------------------------------------
__global__ void __launch_bounds__(256, 8)
k_blur(const float* __restrict__ in,       // null in norm mode
       const float* __restrict__ guide,
       float* __restrict__ outs, float* __restrict__ outb,
       const float* __restrict__ rsn, const float* __restrict__ rbn,
       const float* __restrict__ d1, const float* __restrict__ d2,
       const int* __restrict__ dflag,
       const float* __restrict__ kbuf, int norm_mode) {
    __shared__ float vbs[TH][LSTR];
    __shared__ float vbb[TH][LSTR];
    __shared__ float k3s[KS], k10s[KS];
    int t = threadIdx.x;
    if (t < KS) { k3s[t] = kbuf[t]; k10s[t] = kbuf[KS + t]; }
    __syncthreads();

    int c  = blockIdx.z;
    int x0 = blockIdx.x * TW;
    int y0 = blockIdx.y * TH;
    const float* base = in ? (in + (size_t)c*HWN) : nullptr;

    // ---- v-pass: all threads; unit = (col, 8-row half) ----
    for (int u = t; u < 2*TWH; u += 256) {
        int col  = (u < TWH) ? u : u - TWH;
        int half = (u < TWH) ? 0 : 1;
        int xg = x0 - RAD + col;
        bool xok = (xg >= 0 && xg < WW);
        int yb = y0 + half*8;                 // first output row (global)
        float ws_[KS], wb_[KS];
        #pragma unroll
        for (int i = 0; i < KS-1; ++i) {      // preload rows yb-7 .. yb+6
            int yg = yb - RAD + i;
            bool ok = xok && (yg >= 0) && (yg < HH);
            float v = 0.f, g = 0.f;
            if (ok) { g = guide[yg*WW + xg]; v = base ? base[yg*WW + xg] : 1.0f; }
            ws_[i] = v; wb_[i] = v * g;
        }
        #pragma unroll
        for (int y = 0; y < 8; ++y) {
            int yg = yb + y + RAD;
            bool ok = xok && (yg < HH);
            float v = 0.f, g = 0.f;
            if (ok) { g = guide[yg*WW + xg]; v = base ? base[yg*WW + xg] : 1.0f; }
            ws_[(KS-1+y)%KS] = v; wb_[(KS-1+y)%KS] = v * g;
            float as = 0.f, ab = 0.f;
            #pragma unroll
            for (int d = 0; d < KS; ++d) {
                as += k3s[d]  * ws_[(y+d)%KS];
                ab += k10s[d] * wb_[(y+d)%KS];
            }
            vbs[half*8 + y][col] = as; vbb[half*8 + y][col] = ab;
        }
    }
    __syncthreads();

    // ---- h-pass: 8 outputs per thread ----
    int oy = t & 15;
    int xs = (t >> 4) * 8;
    int gy = y0 + oy;
    int rowp = gy*WW + x0 + xs;
    size_t ob = (size_t)c*HWN + rowp;

    float wS[22], wB[22];
    #pragma unroll
    for (int i = 0; i < 22; ++i) { wS[i] = vbs[oy][xs + i]; wB[i] = vbb[oy][xs + i]; }

    float resS[8], resB[8];
    #pragma unroll
    for (int j = 0; j < 8; ++j) {
        float a = 0.f, b = 0.f;
        #pragma unroll
        for (int d = 0; d < KS; ++d) { a += k3s[d] * wS[j + d]; b += k10s[d] * wB[j + d]; }
        resS[j] = a; resB[j] = b;
    }

    if (norm_mode) {
        #pragma unroll
        for (int j = 0; j < 8; ++j) {
            outs[rowp + j] = 1.0f / resS[j];
            outb[rowp + j] = 1.0f / resB[j];
        }
    } else if (dflag[0]) {
        float d1c = d1[c], d2c = d2[c];
        #pragma unroll
        for (int j = 0; j < 8; ++j)
            outs[ob + j] = d1c * resS[j] * rsn[rowp + j]
                         + d2c * resB[j] * rbn[rowp + j];
    } else {
        #pragma unroll
        for (int j = 0; j < 8; ++j) {
            outs[ob + j] = resS[j] * rsn[rowp + j];
            outb[ob + j] = resB[j] * rbn[rowp + j];
        }
    }
}

// ---------------------------------------------------------------------------
// q_{i+1} = u - pairwise - cru(q_i); then (unless last) softmax + clique
// reduction for iter i+1.  q is read/written ONLY at clique pixels.
// diag mode: pw = combined pairwise plane; dense: pw=spatial, blo=bilateral.
// ---------------------------------------------------------------------------
__global__ void __launch_bounds__(256, 6)
k_update(const float* __restrict__ un,
         const float* __restrict__ qin,   // == un on iter 0, else q (sparse-valid)
         const float* __restrict__ pw,
         const float* __restrict__ blo,
         const float* __restrict__ M1t,   // [k][c]
         const float* __restrict__ M2t,
         const int* __restrict__ dflag,
         const float* __restrict__ sums_cur,
         float* __restrict__ sums_next,
         const float* __restrict__ lwg,
         const float* __restrict__ hwg,
         const int* __restrict__ spmT,
         const int* __restrict__ spidx, int iter,
         float* __restrict__ q,
         float* __restrict__ sm,
         float* __restrict__ out, int last) {
    __shared__ float slse[3*CC];
    if (threadIdx.x < 3*CC) {
        float s = 0.f;
        #pragma unroll
        for (int b = 0; b < NBKT; ++b) s += sums_cur[b*64 + threadIdx.x];
        slse[threadIdx.x] = FLOG((float)HWN + s);
    }
    __syncthreads();

    int p = blockIdx.x * blockDim.x + threadIdx.x;
    int sidx = spidx[iter];
    int s = spmT[p];
    float f1 = (s == sidx)     ? 1.f : 0.f;
    float f2 = (s == sidx + 1) ? 1.f : 0.f;

    float acc[CC];
    if (dflag[0]) {
        #pragma unroll
        for (int c = 0; c < CC; ++c) acc[c] = pw[c*HWN + p];
    } else {
        #pragma unroll
        for (int c = 0; c < CC; ++c) acc[c] = 0.f;
        #pragma unroll
        for (int k = 0; k < CC; ++k) {
            float sv = pw[k*HWN + p];
            float bv = blo[k*HWN + p];
            #pragma unroll
            for (int c = 0; c < CC; ++c)
                acc[c] += M1t[k*CC + c] * sv + M2t[k*CC + c] * bv;
        }
    }

    float hw0 = hwg[0], hw1 = hwg[1], hw2 = hwg[2];
    bool any_clique = __any(f1 != 0.f || f2 != 0.f);
    if (any_clique) {
        float v[CC];
        #pragma unroll
        for (int c = 0; c < CC; ++c) v[c] = qin[p*CC + c];
        float mx = v[0];
        #pragma unroll
        for (int c = 1; c < CC; ++c) mx = fmaxf(mx, v[c]);
        #pragma unroll
        for (int c = 0; c < CC; ++c) {
            float qv = v[c];
            float qmod = qv + ((qv == 0.f) ? 1.f : 0.f);
            float anp = f1 * (qv + mx) - ((f1 != 0.f && qv == mx) ? qv : 0.f);
            float qst = anp + ((anp == 0.f) ? 1.f : 0.f);
            float p1 = f1 * slse[c];
            float p2 = f1 * slse[CC + c];
            float p3 = p1 + f2 * slse[2*CC + c];
            float ft1 = p1 * FRCP(qmod);
            float ft2 = p2 * FRCP(qst);
            float ft3 = p3 * FRCP(qmod);
            float cru = lwg[c]*ft1        + hw0*(1.f - ft1)
                      + lwg[CC + c]*ft2   + hw1*(1.f - ft2)
                      + lwg[2*CC + c]*ft3 + hw2*(1.f - ft3);
            acc[c] = un[p*CC + c] - acc[c] - cru;
        }
    } else {
        float cruc = hw0 + hw1 + hw2;   // all ft == 0
        #pragma unroll
        for (int c = 0; c < CC; ++c)
            acc[c] = un[p*CC + c] - acc[c] - cruc;
    }

    if (!last) {
        int sidx2 = spidx[iter + 1];
        bool c1 = (s == sidx2), c2 = (s == sidx2 + 1);
        if (c1 || c2) {
            // next iter's cru needs q only at its clique pixels
            #pragma unroll
            for (int c = 0; c < CC; ++c) q[p*CC + c] = acc[c];
        }
        float mx2 = acc[0];
        #pragma unroll
        for (int c = 1; c < CC; ++c) mx2 = fmaxf(mx2, acc[c]);
        float e[CC], ssum = 0.f;
        #pragma unroll
        for (int c = 0; c < CC; ++c) { e[c] = FEXP(acc[c] - mx2); ssum += e[c]; }
        float inv = FRCP(ssum);
        #pragma unroll
        for (int c = 0; c < CC; ++c) sm[c*HWN + p] = e[c] * inv;

        if (c1 || c2) {
            float* bkt = sums_next + (blockIdx.x & (NBKT-1)) * 64;
            float emx = FEXP(mx2);
            if (c1) {
                #pragma unroll
                for (int c = 0; c < CC; ++c) {
                    float ev = e[c] * emx;
                    atomicAdd(&bkt[c], ev - 1.0f);
                    float ea = (acc[c] == mx2) ? emx : ev * emx;
                    atomicAdd(&bkt[CC + c], ea - 1.0f);
                }
            } else {
                #pragma unroll
                for (int c = 0; c < CC; ++c) atomicAdd(&bkt[2*CC + c], e[c] * emx - 1.0f);
            }
        }
    } else {
        #pragma unroll
        for (int c = 0; c < CC; ++c) out[p*CC + c] = acc[c];
    }
}

// ---------------------------------------------------------------------------
extern "C" void kernel_launch(void* const* d_in, const int* in_sizes, int n_in,
                              void* d_out, int out_size, void* d_ws, size_t ws_size,
                              hipStream_t stream) {
    const float* un    = (const float*)d_in[0];
    const float* rgb   = (const float*)d_in[1];
    const int*   spin  = (const int*)  d_in[2];
    const int*   spidx = (const int*)  d_in[3];
    const float* skw   = (const float*)d_in[4];
    const float* bkw   = (const float*)d_in[5];
    const float* lw    = (const float*)d_in[6];
    const float* hwv   = (const float*)d_in[7];
    const float* cm    = (const float*)d_in[8];
    float* out = (float*)d_out;

    float* ws = (float*)d_ws;
    float* q     = ws;                     // pixel-major, sparse-valid
    float* sm    = ws + (size_t)CHW;       // channel-planar
    float* a     = ws + (size_t)2*CHW;     // combined pairwise (diag) / spatial
    float* b     = ws + (size_t)3*CHW;     // bilateral (dense fallback)
    float* guide = ws + (size_t)4*CHW;
    float* rsn   = guide + HWN;            // reciprocal norms
    float* rbn   = rsn + HWN;
    int*   spmT  = (int*)(rbn + HWN);
    float* M1t   = rbn + 2*(size_t)HWN;    // after spmT (HWN ints)
    float* M2t   = M1t + CC*CC;
    float* d1    = M2t + CC*CC;
    float* d2    = d1 + CC;
    int*   dflag = (int*)(d2 + CC);
    float* kbuf  = d2 + CC + 4;
    float* sums  = kbuf + 2*KS;            // NITER * NBKT * 64 floats

    dim3 blk(256);
    int gpix = HWN / 256;                  // 1024 blocks
    dim3 gblur(WW/TW, HH/TH, CC);          // 4 x 32 x 21
    dim3 gnorm(WW/TW, HH/TH, 1);

    k_init_small<<<1, 512, 0, stream>>>(cm, skw, bkw, M1t, M2t, d1, d2, dflag,
                                        kbuf, sums);
    k_init_maps<<<gpix, blk, 0, stream>>>(rgb, spin, un, guide, spmT, sm,
                                          spidx, sums);
    k_blur<<<gnorm, blk, 0, stream>>>(nullptr, guide, rsn, rbn,
                                      nullptr, nullptr, d1, d2, dflag, kbuf, 1);

    for (int it = 0; it < NITER; ++it) {
        int last = (it == NITER - 1) ? 1 : 0;
        float* su  = sums + it*NBKT*64;
        float* sun = last ? nullptr : (sums + (it+1)*NBKT*64);
        const float* qin = (it == 0) ? un : q;
        k_blur<<<gblur, blk, 0, stream>>>(sm, guide, a, b, rsn, rbn,
                                          d1, d2, dflag, kbuf, 0);
        k_update<<<gpix, blk, 0, stream>>>(un, qin, a, b, M1t, M2t, dflag,
                                           su, sun, lw, hwv,
                                           spmT, spidx, it, q, sm, out, last);
    }
}

// Round 9
// 415.163 us; speedup vs baseline: 2.1450x; 2.1450x over previous
//
#include <hip/hip_runtime.h>
#include <math.h>

#define CC 21
#define HH 512
#define WW 512
#define HWN (HH*WW)
#define CHW (CC*HWN)
#define RAD 7
#define KS 15
#define NITER 5
#define NBKT 16

#define TW 128
#define TH 16
#define TWH (TW + 2*RAD)   // 142
#define LSTR 145           // odd LDS row stride

#define FEXP(x) __expf(x)
#define FLOG(x) __logf(x)
#define FRCP(x) __builtin_amdgcn_rcpf(x)

typedef unsigned short ushort_t;
typedef unsigned int uint_t;

__device__ __forceinline__ float b2f(ushort_t u) {
    return __uint_as_float(((uint_t)u) << 16);
}
__device__ __forceinline__ ushort_t f2b(float f) {
    uint_t u = __float_as_uint(f);
    u += 0x7FFFu + ((u >> 16) & 1u);   // round to nearest even
    return (ushort_t)(u >> 16);
}

// ---------------------------------------------------------------------------
// init: M1t/M2t, diag extracts + flag, taps, zero sums (all parallel)
// ---------------------------------------------------------------------------
__global__ void k_init_small(const float* __restrict__ cm,
                             const float* __restrict__ skw,
                             const float* __restrict__ bkw,
                             float* __restrict__ M1t, float* __restrict__ M2t,
                             float* __restrict__ d1, float* __restrict__ d2,
                             int* __restrict__ dflag,
                             float* __restrict__ kbuf,
                             float* __restrict__ sums) {
    __shared__ int sbad;
    int t = threadIdx.x;
    if (t == 0) sbad = 0;
    __syncthreads();
    if (t < CC*CC) {
        int k = t / CC, c = t % CC;
        float a = 0.f, b = 0.f;
        for (int m = 0; m < CC; ++m) {
            a += cm[c*CC+m] * skw[m*CC+k];
            b += cm[c*CC+m] * bkw[m*CC+k];
        }
        M1t[t] = a; M2t[t] = b;
        if (k != c && (a != 0.f || b != 0.f)) atomicOr(&sbad, 1);
        if (k == c) { d1[c] = a; d2[c] = b; }
    }
    for (int i = t; i < NITER*NBKT*64; i += blockDim.x) sums[i] = 0.f;
    if (t == CC*CC) {
        float w3[KS], w10[KS];
        float s3 = 0.f, s10 = 0.f;
        for (int i = 0; i < KS; ++i) {
            float x = (float)(i - RAD);
            w3[i]  = expf(-0.5f * (x/3.0f)  * (x/3.0f));
            w10[i] = expf(-0.5f * (x/10.0f) * (x/10.0f));
            s3 += w3[i]; s10 += w10[i];
        }
        for (int i = 0; i < KS; ++i) {
            kbuf[i]      = w3[i]  / s3;
            kbuf[KS + i] = w10[i] / s10;
        }
    }
    __syncthreads();
    if (t == 0) dflag[0] = sbad ? 0 : 1;
}

// ---------------------------------------------------------------------------
// guide, spmT, unp (planar f32 copy of un), sm0 = softmax(un) (bf16 planar),
// clique sums for iter 0.
// ---------------------------------------------------------------------------
__global__ void k_init_maps(const float* __restrict__ rgb,
                            const int* __restrict__ spin,
                            const float* __restrict__ un,
                            float* __restrict__ guide,
                            int* __restrict__ spmT,
                            float* __restrict__ unp,
                            ushort_t* __restrict__ sm,
                            const int* __restrict__ spidx,
                            float* __restrict__ sums0) {
    int p = blockIdx.x * blockDim.x + threadIdx.x;
    int h = p / WW, w = p - h*WW;
    float r = rgb[p*3+0] * (1.0f/255.0f);
    float g = rgb[p*3+1] * (1.0f/255.0f);
    float b = rgb[p*3+2] * (1.0f/255.0f);
    guide[p] = FEXP(-0.5f * (r*r + g*g + b*b) / 9.0f);   // theta_beta^2 = 9
    int s = spin[w*HH + h];
    spmT[p] = s;
    float v[CC];
    #pragma unroll
    for (int c = 0; c < CC; ++c) { v[c] = un[p*CC + c]; unp[c*HWN + p] = v[c]; }
    float mx = v[0];
    #pragma unroll
    for (int c = 1; c < CC; ++c) mx = fmaxf(mx, v[c]);
    float e[CC], ssum = 0.f;
    #pragma unroll
    for (int c = 0; c < CC; ++c) { e[c] = FEXP(v[c] - mx); ssum += e[c]; }
    float inv = FRCP(ssum);
    #pragma unroll
    for (int c = 0; c < CC; ++c) sm[c*HWN + p] = f2b(e[c] * inv);

    int sidx = spidx[0];
    bool c1 = (s == sidx), c2 = (s == sidx + 1);
    if (c1 || c2) {
        float* bkt = sums0 + (blockIdx.x & (NBKT-1)) * 64;
        float emx = FEXP(mx);
        if (c1) {
            #pragma unroll
            for (int c = 0; c < CC; ++c) {
                float ev = e[c] * emx;                       // exp(q)
                atomicAdd(&bkt[c], ev - 1.0f);
                float ea = (v[c] == mx) ? emx : ev * emx;    // exp(A_np)
                atomicAdd(&bkt[CC + c], ea - 1.0f);
            }
        } else {
            #pragma unroll
            for (int c = 0; c < CC; ++c) atomicAdd(&bkt[2*CC + c], e[c] * emx - 1.0f);
        }
    }
}

// ---------------------------------------------------------------------------
// norm pass: blur(1) and blur(guide) -> write reciprocal norms (f32).
// ---------------------------------------------------------------------------
__global__ void __launch_bounds__(256, 4)
k_norm(const float* __restrict__ guide,
       float* __restrict__ rsn, float* __restrict__ rbn,
       const float* __restrict__ kbuf) {
    __shared__ float vbs[TH][LSTR];
    __shared__ float vbb[TH][LSTR];
    __shared__ float k3s[KS], k10s[KS];
    int t = threadIdx.x;
    if (t < KS) { k3s[t] = kbuf[t]; k10s[t] = kbuf[KS + t]; }
    __syncthreads();

    int x0 = blockIdx.x * TW;
    int y0 = blockIdx.y * TH;

    for (int u = t; u < 2*TWH; u += 256) {
        int col  = (u < TWH) ? u : u - TWH;
        int half = (u < TWH) ? 0 : 1;
        int xg = x0 - RAD + col;
        bool xok = (xg >= 0 && xg < WW);
        int yb = y0 + half*8;
        float ws_[KS], wb_[KS];
        #pragma unroll
        for (int i = 0; i < KS-1; ++i) {
            int yg = yb - RAD + i;
            bool ok = xok && (yg >= 0) && (yg < HH);
            float v = ok ? 1.0f : 0.f;
            float g = ok ? guide[yg*WW + xg] : 0.f;
            ws_[i] = v; wb_[i] = g;
        }
        #pragma unroll
        for (int y = 0; y < 8; ++y) {
            int yg = yb + y + RAD;
            bool ok = xok && (yg < HH);
            float v = ok ? 1.0f : 0.f;
            float g = ok ? guide[yg*WW + xg] : 0.f;
            ws_[(KS-1+y)%KS] = v; wb_[(KS-1+y)%KS] = g;
            float as = 0.f, ab = 0.f;
            #pragma unroll
            for (int d = 0; d < KS; ++d) {
                as += k3s[d]  * ws_[(y+d)%KS];
                ab += k10s[d] * wb_[(y+d)%KS];
            }
            vbs[half*8 + y][col] = as; vbb[half*8 + y][col] = ab;
        }
    }
    __syncthreads();

    int oy = t & 15;
    int xs = (t >> 4) * 8;
    int rowp = (y0 + oy)*WW + x0 + xs;

    float wS[22], wB[22];
    #pragma unroll
    for (int i = 0; i < 22; ++i) { wS[i] = vbs[oy][xs + i]; wB[i] = vbb[oy][xs + i]; }
    #pragma unroll
    for (int j = 0; j < 8; ++j) {
        float a = 0.f, b = 0.f;
        #pragma unroll
        for (int d = 0; d < KS; ++d) { a += k3s[d] * wS[j + d]; b += k10s[d] * wB[j + d]; }
        rsn[rowp + j] = 1.0f / a;
        rbn[rowp + j] = 1.0f / b;
    }
}

// ---------------------------------------------------------------------------
// fused separable blur on bf16 sm planes. tile 128x16. v-pass: 284 units over
// 256 threads (register sliding window). h-pass: oy=t&15, xs=(t>>4)*8.
// diag -> combined bf16 pairwise plane; dense -> two bf16 planes.
// ---------------------------------------------------------------------------
__global__ void __launch_bounds__(256, 4)
k_blur(const ushort_t* __restrict__ in,
       const float* __restrict__ guide,
       ushort_t* __restrict__ outs, ushort_t* __restrict__ outb,
       const float* __restrict__ rsn, const float* __restrict__ rbn,
       const float* __restrict__ d1, const float* __restrict__ d2,
       const int* __restrict__ dflag,
       const float* __restrict__ kbuf) {
    __shared__ float vbs[TH][LSTR];
    __shared__ float vbb[TH][LSTR];
    __shared__ float k3s[KS], k10s[KS];
    int t = threadIdx.x;
    if (t < KS) { k3s[t] = kbuf[t]; k10s[t] = kbuf[KS + t]; }
    __syncthreads();

    int c  = blockIdx.z;
    int x0 = blockIdx.x * TW;
    int y0 = blockIdx.y * TH;
    const ushort_t* base = in + (size_t)c*HWN;

    // ---- v-pass: all threads; unit = (col, 8-row half) ----
    for (int u = t; u < 2*TWH; u += 256) {
        int col  = (u < TWH) ? u : u - TWH;
        int half = (u < TWH) ? 0 : 1;
        int xg = x0 - RAD + col;
        bool xok = (xg >= 0 && xg < WW);
        int yb = y0 + half*8;
        float ws_[KS], wb_[KS];
        #pragma unroll
        for (int i = 0; i < KS-1; ++i) {
            int yg = yb - RAD + i;
            bool ok = xok && (yg >= 0) && (yg < HH);
            float v = 0.f, g = 0.f;
            if (ok) { g = guide[yg*WW + xg]; v = b2f(base[yg*WW + xg]); }
            ws_[i] = v; wb_[i] = v * g;
        }
        #pragma unroll
        for (int y = 0; y < 8; ++y) {
            int yg = yb + y + RAD;
            bool ok = xok && (yg < HH);
            float v = 0.f, g = 0.f;
            if (ok) { g = guide[yg*WW + xg]; v = b2f(base[yg*WW + xg]); }
            ws_[(KS-1+y)%KS] = v; wb_[(KS-1+y)%KS] = v * g;
            float as = 0.f, ab = 0.f;
            #pragma unroll
            for (int d = 0; d < KS; ++d) {
                as += k3s[d]  * ws_[(y+d)%KS];
                ab += k10s[d] * wb_[(y+d)%KS];
            }
            vbs[half*8 + y][col] = as; vbb[half*8 + y][col] = ab;
        }
    }
    __syncthreads();

    // ---- h-pass: 8 outputs per thread ----
    int oy = t & 15;
    int xs = (t >> 4) * 8;
    int gy = y0 + oy;
    int rowp = gy*WW + x0 + xs;
    size_t ob = (size_t)c*HWN + rowp;

    float wS[22], wB[22];
    #pragma unroll
    for (int i = 0; i < 22; ++i) { wS[i] = vbs[oy][xs + i]; wB[i] = vbb[oy][xs + i]; }

    float resS[8], resB[8];
    #pragma unroll
    for (int j = 0; j < 8; ++j) {
        float a = 0.f, b = 0.f;
        #pragma unroll
        for (int d = 0; d < KS; ++d) { a += k3s[d] * wS[j + d]; b += k10s[d] * wB[j + d]; }
        resS[j] = a; resB[j] = b;
    }

    if (dflag[0]) {
        float d1c = d1[c], d2c = d2[c];
        #pragma unroll
        for (int j = 0; j < 8; ++j)
            outs[ob + j] = f2b(d1c * resS[j] * rsn[rowp + j]
                             + d2c * resB[j] * rbn[rowp + j]);
    } else {
        #pragma unroll
        for (int j = 0; j < 8; ++j) {
            outs[ob + j] = f2b(resS[j] * rsn[rowp + j]);
            outb[ob + j] = f2b(resB[j] * rbn[rowp + j]);
        }
    }
}

// ---------------------------------------------------------------------------
// q_{i+1} = u - pairwise - cru(q_i); then (unless last) softmax + clique
// reduction for iter i+1.  unp planar f32; pw bf16 planar; sm bf16 planar;
// q pixel-major f32 (clique-sparse).
// ---------------------------------------------------------------------------
__global__ void __launch_bounds__(256, 4)
k_update(const float* __restrict__ unp,
         const float* __restrict__ qin,   // == un (pixel-major) on iter 0, else q
         int qin_pixelmajor_unused,
         const ushort_t* __restrict__ pw,
         const ushort_t* __restrict__ blo,
         const float* __restrict__ M1t,   // [k][c]
         const float* __restrict__ M2t,
         const int* __restrict__ dflag,
         const float* __restrict__ sums_cur,
         float* __restrict__ sums_next,
         const float* __restrict__ lwg,
         const float* __restrict__ hwg,
         const int* __restrict__ spmT,
         const int* __restrict__ spidx, int iter,
         float* __restrict__ q,
         ushort_t* __restrict__ sm,
         float* __restrict__ out, int last) {
    __shared__ float slse[3*CC];
    if (threadIdx.x < 3*CC) {
        float s = 0.f;
        #pragma unroll
        for (int b = 0; b < NBKT; ++b) s += sums_cur[b*64 + threadIdx.x];
        slse[threadIdx.x] = FLOG((float)HWN + s);
    }
    __syncthreads();

    int p = blockIdx.x * blockDim.x + threadIdx.x;
    int sidx = spidx[iter];
    int s = spmT[p];
    float f1 = (s == sidx)     ? 1.f : 0.f;
    float f2 = (s == sidx + 1) ? 1.f : 0.f;

    float acc[CC];
    if (dflag[0]) {
        #pragma unroll
        for (int c = 0; c < CC; ++c) acc[c] = b2f(pw[c*HWN + p]);
    } else {
        #pragma unroll
        for (int c = 0; c < CC; ++c) acc[c] = 0.f;
        #pragma unroll
        for (int k = 0; k < CC; ++k) {
            float sv = b2f(pw[k*HWN + p]);
            float bv = b2f(blo[k*HWN + p]);
            #pragma unroll
            for (int c = 0; c < CC; ++c)
                acc[c] += M1t[k*CC + c] * sv + M2t[k*CC + c] * bv;
        }
    }

    float hw0 = hwg[0], hw1 = hwg[1], hw2 = hwg[2];
    bool any_clique = __any(f1 != 0.f || f2 != 0.f);
    if (any_clique) {
        float v[CC];
        #pragma unroll
        for (int c = 0; c < CC; ++c) v[c] = qin[p*CC + c];
        float mx = v[0];
        #pragma unroll
        for (int c = 1; c < CC; ++c) mx = fmaxf(mx, v[c]);
        #pragma unroll
        for (int c = 0; c < CC; ++c) {
            float qv = v[c];
            float qmod = qv + ((qv == 0.f) ? 1.f : 0.f);
            float anp = f1 * (qv + mx) - ((f1 != 0.f && qv == mx) ? qv : 0.f);
            float qst = anp + ((anp == 0.f) ? 1.f : 0.f);
            float p1 = f1 * slse[c];
            float p2 = f1 * slse[CC + c];
            float p3 = p1 + f2 * slse[2*CC + c];
            float ft1 = p1 * FRCP(qmod);
            float ft2 = p2 * FRCP(qst);
            float ft3 = p3 * FRCP(qmod);
            float cru = lwg[c]*ft1        + hw0*(1.f - ft1)
                      + lwg[CC + c]*ft2   + hw1*(1.f - ft2)
                      + lwg[2*CC + c]*ft3 + hw2*(1.f - ft3);
            acc[c] = unp[c*HWN + p] - acc[c] - cru;
        }
    } else {
        float cruc = hw0 + hw1 + hw2;   // all ft == 0
        #pragma unroll
        for (int c = 0; c < CC; ++c)
            acc[c] = unp[c*HWN + p] - acc[c] - cruc;
    }

    if (!last) {
        int sidx2 = spidx[iter + 1];
        bool c1 = (s == sidx2), c2 = (s == sidx2 + 1);
        if (c1 || c2) {
            // next iter's cru needs q only at its clique pixels
            #pragma unroll
            for (int c = 0; c < CC; ++c) q[p*CC + c] = acc[c];
        }
        float mx2 = acc[0];
        #pragma unroll
        for (int c = 1; c < CC; ++c) mx2 = fmaxf(mx2, acc[c]);
        float e[CC], ssum = 0.f;
        #pragma unroll
        for (int c = 0; c < CC; ++c) { e[c] = FEXP(acc[c] - mx2); ssum += e[c]; }
        float inv = FRCP(ssum);
        #pragma unroll
        for (int c = 0; c < CC; ++c) sm[c*HWN + p] = f2b(e[c] * inv);

        if (c1 || c2) {
            float* bkt = sums_next + (blockIdx.x & (NBKT-1)) * 64;
            float emx = FEXP(mx2);
            if (c1) {
                #pragma unroll
                for (int c = 0; c < CC; ++c) {
                    float ev = e[c] * emx;
                    atomicAdd(&bkt[c], ev - 1.0f);
                    float ea = (acc[c] == mx2) ? emx : ev * emx;
                    atomicAdd(&bkt[CC + c], ea - 1.0f);
                }
            } else {
                #pragma unroll
                for (int c = 0; c < CC; ++c) atomicAdd(&bkt[2*CC + c], e[c] * emx - 1.0f);
            }
        }
    } else {
        #pragma unroll
        for (int c = 0; c < CC; ++c) out[p*CC + c] = acc[c];
    }
}

// ---------------------------------------------------------------------------
extern "C" void kernel_launch(void* const* d_in, const int* in_sizes, int n_in,
                              void* d_out, int out_size, void* d_ws, size_t ws_size,
                              hipStream_t stream) {
    const float* un    = (const float*)d_in[0];
    const float* rgb   = (const float*)d_in[1];
    const int*   spin  = (const int*)  d_in[2];
    const int*   spidx = (const int*)  d_in[3];
    const float* skw   = (const float*)d_in[4];
    const float* bkw   = (const float*)d_in[5];
    const float* lw    = (const float*)d_in[6];
    const float* hwv   = (const float*)d_in[7];
    const float* cm    = (const float*)d_in[8];
    float* out = (float*)d_out;

    float* ws = (float*)d_ws;
    float*    q    = ws;                               // pixel-major f32 (sparse)
    float*    unp  = ws + (size_t)CHW;                 // planar f32
    ushort_t* smb  = (ushort_t*)(ws + (size_t)2*CHW);  // bf16 planar (CHW ushorts)
    ushort_t* pwa  = smb + (size_t)CHW;                // bf16 planar
    ushort_t* pwb  = pwa + (size_t)CHW;                // bf16 planar (dense mode)
    float* guide = ws + (size_t)2*CHW + ((size_t)3*CHW + 1)/2;  // after 3 ushort planes
    float* rsn   = guide + HWN;
    float* rbn   = rsn + HWN;
    int*   spmT  = (int*)(rbn + HWN);
    float* M1t   = rbn + 2*(size_t)HWN;                // after spmT (HWN ints)
    float* M2t   = M1t + CC*CC;
    float* d1    = M2t + CC*CC;
    float* d2    = d1 + CC;
    int*   dflag = (int*)(d2 + CC);
    float* kbuf  = d2 + CC + 4;
    float* sums  = kbuf + 2*KS;                        // NITER * NBKT * 64 floats

    dim3 blk(256);
    int gpix = HWN / 256;                  // 1024 blocks
    dim3 gblur(WW/TW, HH/TH, CC);          // 4 x 32 x 21
    dim3 gnorm(WW/TW, HH/TH, 1);

    k_init_small<<<1, 512, 0, stream>>>(cm, skw, bkw, M1t, M2t, d1, d2, dflag,
                                        kbuf, sums);
    k_init_maps<<<gpix, blk, 0, stream>>>(rgb, spin, un, guide, spmT, unp, smb,
                                          spidx, sums);
    k_norm<<<gnorm, blk, 0, stream>>>(guide, rsn, rbn, kbuf);

    for (int it = 0; it < NITER; ++it) {
        int last = (it == NITER - 1) ? 1 : 0;
        float* su  = sums + it*NBKT*64;
        float* sun = last ? nullptr : (sums + (it+1)*NBKT*64);
        const float* qin = (it == 0) ? un : q;
        k_blur<<<gblur, blk, 0, stream>>>(smb, guide, pwa, pwb, rsn, rbn,
                                          d1, d2, dflag, kbuf);
        k_update<<<gpix, blk, 0, stream>>>(unp, qin, 0, pwa, pwb, M1t, M2t, dflag,
                                           su, sun, lw, hwv,
                                           spmT, spidx, it, q, smb, out, last);
    }
}

// Round 10
// 410.434 us; speedup vs baseline: 2.1697x; 1.0115x over previous
//
#include <hip/hip_runtime.h>
#include <math.h>

#define CC 21
#define HH 512
#define WW 512
#define HWN (HH*WW)
#define HPN (HWN/2)
#define CHW (CC*HWN)
#define RAD 7
#define KS 15
#define NITER 5
#define NBKT 16

#define TW 128
#define TH 16
#define TWH (TW + 2*RAD)   // 142
#define LSTR 145           // odd LDS row stride

#define FEXP(x) __expf(x)
#define FLOG(x) __logf(x)
#define FRCP(x) __builtin_amdgcn_rcpf(x)

typedef unsigned short ushort_t;
typedef unsigned int uint_t;

__device__ __forceinline__ float b2f(ushort_t u) {
    return __uint_as_float(((uint_t)u) << 16);
}
__device__ __forceinline__ ushort_t f2b(float f) {
    uint_t u = __float_as_uint(f);
    u += 0x7FFFu + ((u >> 16) & 1u);   // round to nearest even
    return (ushort_t)(u >> 16);
}

// ---------------------------------------------------------------------------
// init: M1t/M2t, diag extracts + flag, taps, zero sums (all parallel)
// ---------------------------------------------------------------------------
__global__ void k_init_small(const float* __restrict__ cm,
                             const float* __restrict__ skw,
                             const float* __restrict__ bkw,
                             float* __restrict__ M1t, float* __restrict__ M2t,
                             float* __restrict__ d1, float* __restrict__ d2,
                             int* __restrict__ dflag,
                             float* __restrict__ kbuf,
                             float* __restrict__ sums) {
    __shared__ int sbad;
    int t = threadIdx.x;
    if (t == 0) sbad = 0;
    __syncthreads();
    if (t < CC*CC) {
        int k = t / CC, c = t % CC;
        float a = 0.f, b = 0.f;
        for (int m = 0; m < CC; ++m) {
            a += cm[c*CC+m] * skw[m*CC+k];
            b += cm[c*CC+m] * bkw[m*CC+k];
        }
        M1t[t] = a; M2t[t] = b;
        if (k != c && (a != 0.f || b != 0.f)) atomicOr(&sbad, 1);
        if (k == c) { d1[c] = a; d2[c] = b; }
    }
    for (int i = t; i < NITER*NBKT*64; i += blockDim.x) sums[i] = 0.f;
    if (t == CC*CC) {
        float w3[KS], w10[KS];
        float s3 = 0.f, s10 = 0.f;
        for (int i = 0; i < KS; ++i) {
            float x = (float)(i - RAD);
            w3[i]  = expf(-0.5f * (x/3.0f)  * (x/3.0f));
            w10[i] = expf(-0.5f * (x/10.0f) * (x/10.0f));
            s3 += w3[i]; s10 += w10[i];
        }
        for (int i = 0; i < KS; ++i) {
            kbuf[i]      = w3[i]  / s3;
            kbuf[KS + i] = w10[i] / s10;
        }
    }
    __syncthreads();
    if (t == 0) dflag[0] = sbad ? 0 : 1;
}

// ---------------------------------------------------------------------------
// guide, spmT, unp (planar f32), sm0 = softmax(un) (bf16 planar), clique sums
// for iter 0.  un read coalesced via float4->LDS staging.
// ---------------------------------------------------------------------------
__global__ void __launch_bounds__(256, 4)
k_init_maps(const float* __restrict__ rgb,
            const int* __restrict__ spin,
            const float* __restrict__ un,
            float* __restrict__ guide,
            int* __restrict__ spmT,
            float* __restrict__ unp,
            ushort_t* __restrict__ sm,
            const int* __restrict__ spidx,
            float* __restrict__ sums0) {
    __shared__ float lun[256*CC];
    {
        const float4* src = (const float4*)(un + (size_t)blockIdx.x*(256*CC));
        float4* dst = (float4*)lun;
        for (int i = threadIdx.x; i < (256*CC)/4; i += 256) dst[i] = src[i];
    }
    __syncthreads();
    int p = blockIdx.x * blockDim.x + threadIdx.x;
    int h = p / WW, w = p - h*WW;
    float r = rgb[p*3+0] * (1.0f/255.0f);
    float g = rgb[p*3+1] * (1.0f/255.0f);
    float b = rgb[p*3+2] * (1.0f/255.0f);
    guide[p] = FEXP(-0.5f * (r*r + g*g + b*b) / 9.0f);   // theta_beta^2 = 9
    int s = spin[w*HH + h];
    spmT[p] = s;
    int tb = threadIdx.x * CC;
    float v[CC];
    #pragma unroll
    for (int c = 0; c < CC; ++c) { v[c] = lun[tb + c]; unp[c*HWN + p] = v[c]; }
    float mx = v[0];
    #pragma unroll
    for (int c = 1; c < CC; ++c) mx = fmaxf(mx, v[c]);
    float e[CC], ssum = 0.f;
    #pragma unroll
    for (int c = 0; c < CC; ++c) { e[c] = FEXP(v[c] - mx); ssum += e[c]; }
    float inv = FRCP(ssum);
    #pragma unroll
    for (int c = 0; c < CC; ++c) sm[c*HWN + p] = f2b(e[c] * inv);

    int sidx = spidx[0];
    bool c1 = (s == sidx), c2 = (s == sidx + 1);
    if (c1 || c2) {
        float* bkt = sums0 + (blockIdx.x & (NBKT-1)) * 64;
        float emx = FEXP(mx);
        if (c1) {
            #pragma unroll
            for (int c = 0; c < CC; ++c) {
                float ev = e[c] * emx;                       // exp(q)
                atomicAdd(&bkt[c], ev - 1.0f);
                float ea = (v[c] == mx) ? emx : ev * emx;    // exp(A_np)
                atomicAdd(&bkt[CC + c], ea - 1.0f);
            }
        } else {
            #pragma unroll
            for (int c = 0; c < CC; ++c) atomicAdd(&bkt[2*CC + c], e[c] * emx - 1.0f);
        }
    }
}

// ---------------------------------------------------------------------------
// norm pass: blur(1) and blur(guide) -> write reciprocal norms (f32).
// ---------------------------------------------------------------------------
__global__ void __launch_bounds__(256, 4)
k_norm(const float* __restrict__ guide,
       float* __restrict__ rsn, float* __restrict__ rbn,
       const float* __restrict__ kbuf) {
    __shared__ float vbs[TH][LSTR];
    __shared__ float vbb[TH][LSTR];
    __shared__ float k3s[KS], k10s[KS];
    int t = threadIdx.x;
    if (t < KS) { k3s[t] = kbuf[t]; k10s[t] = kbuf[KS + t]; }
    __syncthreads();

    int x0 = blockIdx.x * TW;
    int y0 = blockIdx.y * TH;

    for (int u = t; u < 2*TWH; u += 256) {
        int col  = (u < TWH) ? u : u - TWH;
        int half = (u < TWH) ? 0 : 1;
        int xg = x0 - RAD + col;
        bool xok = (xg >= 0 && xg < WW);
        int yb = y0 + half*8;
        float vv[22], gg[22];
        #pragma unroll
        for (int i = 0; i < 22; ++i) {
            int yg = yb - RAD + i;
            bool ok = xok && (yg >= 0) && (yg < HH);
            vv[i] = ok ? 1.0f : 0.f;
            gg[i] = ok ? guide[yg*WW + xg] : 0.f;
        }
        #pragma unroll
        for (int y = 0; y < 8; ++y) {
            float as = 0.f, ab = 0.f;
            #pragma unroll
            for (int d = 0; d < KS; ++d) {
                as += k3s[d]  * vv[y + d];
                ab += k10s[d] * gg[y + d];
            }
            vbs[half*8 + y][col] = as; vbb[half*8 + y][col] = ab;
        }
    }
    __syncthreads();

    int oy = t & 15;
    int xs = (t >> 4) * 8;
    int rowp = (y0 + oy)*WW + x0 + xs;

    float wS[22], wB[22];
    #pragma unroll
    for (int i = 0; i < 22; ++i) { wS[i] = vbs[oy][xs + i]; wB[i] = vbb[oy][xs + i]; }
    #pragma unroll
    for (int j = 0; j < 8; ++j) {
        float a = 0.f, b = 0.f;
        #pragma unroll
        for (int d = 0; d < KS; ++d) { a += k3s[d] * wS[j + d]; b += k10s[d] * wB[j + d]; }
        rsn[rowp + j] = 1.0f / a;
        rbn[rowp + j] = 1.0f / b;
    }
}

// ---------------------------------------------------------------------------
// fused separable blur on bf16 sm planes. v-pass: load-all-then-compute
// (22 outstanding loads per array -> latency hidden). h-pass unchanged.
// ---------------------------------------------------------------------------
__global__ void __launch_bounds__(256, 4)
k_blur(const ushort_t* __restrict__ in,
       const float* __restrict__ guide,
       ushort_t* __restrict__ outs, ushort_t* __restrict__ outb,
       const float* __restrict__ rsn, const float* __restrict__ rbn,
       const float* __restrict__ d1, const float* __restrict__ d2,
       const int* __restrict__ dflag,
       const float* __restrict__ kbuf) {
    __shared__ float vbs[TH][LSTR];
    __shared__ float vbb[TH][LSTR];
    __shared__ float k3s[KS], k10s[KS];
    int t = threadIdx.x;
    if (t < KS) { k3s[t] = kbuf[t]; k10s[t] = kbuf[KS + t]; }
    __syncthreads();

    int c  = blockIdx.z;
    int x0 = blockIdx.x * TW;
    int y0 = blockIdx.y * TH;
    const ushort_t* base = in + (size_t)c*HWN;

    // ---- v-pass: unit = (col, 8-row half); all loads first, then compute ----
    for (int u = t; u < 2*TWH; u += 256) {
        int col  = (u < TWH) ? u : u - TWH;
        int half = (u < TWH) ? 0 : 1;
        int xg = x0 - RAD + col;
        bool xok = (xg >= 0 && xg < WW);
        int yb = y0 + half*8;
        float vv[22], gg[22];
        #pragma unroll
        for (int i = 0; i < 22; ++i) {
            int yg = yb - RAD + i;
            bool ok = xok && (yg >= 0) && (yg < HH);
            vv[i] = ok ? b2f(base[yg*WW + xg]) : 0.f;
            gg[i] = ok ? guide[yg*WW + xg] : 0.f;
        }
        #pragma unroll
        for (int i = 0; i < 22; ++i) gg[i] *= vv[i];
        #pragma unroll
        for (int y = 0; y < 8; ++y) {
            float as = 0.f, ab = 0.f;
            #pragma unroll
            for (int d = 0; d < KS; ++d) {
                as += k3s[d]  * vv[y + d];
                ab += k10s[d] * gg[y + d];
            }
            vbs[half*8 + y][col] = as; vbb[half*8 + y][col] = ab;
        }
    }
    __syncthreads();

    // ---- h-pass: 8 outputs per thread ----
    int oy = t & 15;
    int xs = (t >> 4) * 8;
    int gy = y0 + oy;
    int rowp = gy*WW + x0 + xs;
    size_t ob = (size_t)c*HWN + rowp;

    float wS[22], wB[22];
    #pragma unroll
    for (int i = 0; i < 22; ++i) { wS[i] = vbs[oy][xs + i]; wB[i] = vbb[oy][xs + i]; }

    float resS[8], resB[8];
    #pragma unroll
    for (int j = 0; j < 8; ++j) {
        float a = 0.f, b = 0.f;
        #pragma unroll
        for (int d = 0; d < KS; ++d) { a += k3s[d] * wS[j + d]; b += k10s[d] * wB[j + d]; }
        resS[j] = a; resB[j] = b;
    }

    if (dflag[0]) {
        float d1c = d1[c], d2c = d2[c];
        #pragma unroll
        for (int j = 0; j < 8; ++j)
            outs[ob + j] = f2b(d1c * resS[j] * rsn[rowp + j]
                             + d2c * resB[j] * rbn[rowp + j]);
    } else {
        #pragma unroll
        for (int j = 0; j < 8; ++j) {
            outs[ob + j] = f2b(resS[j] * rsn[rowp + j]);
            outb[ob + j] = f2b(resB[j] * rbn[rowp + j]);
        }
    }
}

// ---------------------------------------------------------------------------
// q_{i+1} = u - pairwise - cru(q_i); softmax + clique sums for iter i+1.
// TWO pixels per thread: packed bf16 (uint) pw loads / sm stores, float2 unp,
// int2 spmT.  q pixel-major f32, clique-sparse.
// ---------------------------------------------------------------------------
__global__ void __launch_bounds__(256, 3)
k_update(const float* __restrict__ unp,
         const float* __restrict__ qin,   // pixel-major: un on iter 0, else q
         const ushort_t* __restrict__ pw,
         const ushort_t* __restrict__ blo,
         const float* __restrict__ M1t,   // [k][c]
         const float* __restrict__ M2t,
         const int* __restrict__ dflag,
         const float* __restrict__ sums_cur,
         float* __restrict__ sums_next,
         const float* __restrict__ lwg,
         const float* __restrict__ hwg,
         const int* __restrict__ spmT,
         const int* __restrict__ spidx, int iter,
         float* __restrict__ q,
         ushort_t* __restrict__ sm,
         float* __restrict__ out, int last) {
    __shared__ float slse[3*CC];
    if (threadIdx.x < 3*CC) {
        float s = 0.f;
        #pragma unroll
        for (int b = 0; b < NBKT; ++b) s += sums_cur[b*64 + threadIdx.x];
        slse[threadIdx.x] = FLOG((float)HWN + s);
    }
    __syncthreads();

    int j = blockIdx.x * blockDim.x + threadIdx.x;   // pixel-pair index
    int p0 = 2*j, p1 = p0 + 1;
    int sidx = spidx[iter];
    int2 ss = ((const int2*)spmT)[j];
    const uint_t*  pw32  = (const uint_t*)pw;
    const uint_t*  blo32 = (const uint_t*)blo;
    const float2*  unp2  = (const float2*)unp;
    uint_t* sm32 = (uint_t*)sm;

    float fa1 = (ss.x == sidx)     ? 1.f : 0.f;
    float fa2 = (ss.x == sidx + 1) ? 1.f : 0.f;
    float fb1 = (ss.y == sidx)     ? 1.f : 0.f;
    float fb2 = (ss.y == sidx + 1) ? 1.f : 0.f;

    float acc0[CC], acc1[CC];
    if (dflag[0]) {
        #pragma unroll
        for (int c = 0; c < CC; ++c) {
            uint_t w = pw32[c*HPN + j];
            acc0[c] = b2f((ushort_t)(w & 0xFFFFu));
            acc1[c] = b2f((ushort_t)(w >> 16));
        }
    } else {
        #pragma unroll
        for (int c = 0; c < CC; ++c) { acc0[c] = 0.f; acc1[c] = 0.f; }
        for (int k = 0; k < CC; ++k) {
            uint_t wp = pw32[k*HPN + j];
            uint_t wb = blo32[k*HPN + j];
            float s0 = b2f((ushort_t)(wp & 0xFFFFu)), s1 = b2f((ushort_t)(wp >> 16));
            float b0 = b2f((ushort_t)(wb & 0xFFFFu)), b1 = b2f((ushort_t)(wb >> 16));
            #pragma unroll
            for (int c = 0; c < CC; ++c) {
                float m1 = M1t[k*CC + c], m2 = M2t[k*CC + c];
                acc0[c] += m1*s0 + m2*b0;
                acc1[c] += m1*s1 + m2*b1;
            }
        }
    }

    float hw0 = hwg[0], hw1 = hwg[1], hw2 = hwg[2];
    bool any_clique = __any(fa1 + fa2 + fb1 + fb2 != 0.f);
    if (any_clique) {
        float v0[CC], v1[CC];
        #pragma unroll
        for (int c = 0; c < CC; ++c) { v0[c] = qin[p0*CC + c]; v1[c] = qin[p1*CC + c]; }
        float mx0 = v0[0], mx1 = v1[0];
        #pragma unroll
        for (int c = 1; c < CC; ++c) { mx0 = fmaxf(mx0, v0[c]); mx1 = fmaxf(mx1, v1[c]); }
        #pragma unroll
        for (int c = 0; c < CC; ++c) {
            float2 uu = unp2[c*HPN + j];
            {
                float qv = v0[c];
                float qmod = qv + ((qv == 0.f) ? 1.f : 0.f);
                float anp = fa1 * (qv + mx0) - ((fa1 != 0.f && qv == mx0) ? qv : 0.f);
                float qst = anp + ((anp == 0.f) ? 1.f : 0.f);
                float p1v = fa1 * slse[c];
                float p2v = fa1 * slse[CC + c];
                float p3v = p1v + fa2 * slse[2*CC + c];
                float ft1 = p1v * FRCP(qmod);
                float ft2 = p2v * FRCP(qst);
                float ft3 = p3v * FRCP(qmod);
                float cru = lwg[c]*ft1        + hw0*(1.f - ft1)
                          + lwg[CC + c]*ft2   + hw1*(1.f - ft2)
                          + lwg[2*CC + c]*ft3 + hw2*(1.f - ft3);
                acc0[c] = uu.x - acc0[c] - cru;
            }
            {
                float qv = v1[c];
                float qmod = qv + ((qv == 0.f) ? 1.f : 0.f);
                float anp = fb1 * (qv + mx1) - ((fb1 != 0.f && qv == mx1) ? qv : 0.f);
                float qst = anp + ((anp == 0.f) ? 1.f : 0.f);
                float p1v = fb1 * slse[c];
                float p2v = fb1 * slse[CC + c];
                float p3v = p1v + fb2 * slse[2*CC + c];
                float ft1 = p1v * FRCP(qmod);
                float ft2 = p2v * FRCP(qst);
                float ft3 = p3v * FRCP(qmod);
                float cru = lwg[c]*ft1        + hw0*(1.f - ft1)
                          + lwg[CC + c]*ft2   + hw1*(1.f - ft2)
                          + lwg[2*CC + c]*ft3 + hw2*(1.f - ft3);
                acc1[c] = uu.y - acc1[c] - cru;
            }
        }
    } else {
        float cruc = hw0 + hw1 + hw2;   // all ft == 0
        #pragma unroll
        for (int c = 0; c < CC; ++c) {
            float2 uu = unp2[c*HPN + j];
            acc0[c] = uu.x - acc0[c] - cruc;
            acc1[c] = uu.y - acc1[c] - cruc;
        }
    }

    if (!last) {
        int sidx2 = spidx[iter + 1];
        bool c1a = (ss.x == sidx2), c2a = (ss.x == sidx2 + 1);
        bool c1b = (ss.y == sidx2), c2b = (ss.y == sidx2 + 1);
        if (c1a || c2a) {
            #pragma unroll
            for (int c = 0; c < CC; ++c) q[p0*CC + c] = acc0[c];
        }
        if (c1b || c2b) {
            #pragma unroll
            for (int c = 0; c < CC; ++c) q[p1*CC + c] = acc1[c];
        }
        float mx0 = acc0[0], mx1 = acc1[0];
        #pragma unroll
        for (int c = 1; c < CC; ++c) { mx0 = fmaxf(mx0, acc0[c]); mx1 = fmaxf(mx1, acc1[c]); }
        float e0[CC], e1[CC], s0 = 0.f, s1 = 0.f;
        #pragma unroll
        for (int c = 0; c < CC; ++c) {
            e0[c] = FEXP(acc0[c] - mx0); s0 += e0[c];
            e1[c] = FEXP(acc1[c] - mx1); s1 += e1[c];
        }
        float i0 = FRCP(s0), i1 = FRCP(s1);
        #pragma unroll
        for (int c = 0; c < CC; ++c)
            sm32[c*HPN + j] = (uint_t)f2b(e0[c] * i0) | ((uint_t)f2b(e1[c] * i1) << 16);

        if (c1a || c2a) {
            float* bkt = sums_next + (blockIdx.x & (NBKT-1)) * 64;
            float emx = FEXP(mx0);
            if (c1a) {
                #pragma unroll
                for (int c = 0; c < CC; ++c) {
                    float ev = e0[c] * emx;
                    atomicAdd(&bkt[c], ev - 1.0f);
                    float ea = (acc0[c] == mx0) ? emx : ev * emx;
                    atomicAdd(&bkt[CC + c], ea - 1.0f);
                }
            } else {
                #pragma unroll
                for (int c = 0; c < CC; ++c) atomicAdd(&bkt[2*CC + c], e0[c] * emx - 1.0f);
            }
        }
        if (c1b || c2b) {
            float* bkt = sums_next + (blockIdx.x & (NBKT-1)) * 64;
            float emx = FEXP(mx1);
            if (c1b) {
                #pragma unroll
                for (int c = 0; c < CC; ++c) {
                    float ev = e1[c] * emx;
                    atomicAdd(&bkt[c], ev - 1.0f);
                    float ea = (acc1[c] == mx1) ? emx : ev * emx;
                    atomicAdd(&bkt[CC + c], ea - 1.0f);
                }
            } else {
                #pragma unroll
                for (int c = 0; c < CC; ++c) atomicAdd(&bkt[2*CC + c], e1[c] * emx - 1.0f);
            }
        }
    } else {
        #pragma unroll
        for (int c = 0; c < CC; ++c) {
            out[p0*CC + c] = acc0[c];
            out[p1*CC + c] = acc1[c];
        }
    }
}

// ---------------------------------------------------------------------------
extern "C" void kernel_launch(void* const* d_in, const int* in_sizes, int n_in,
                              void* d_out, int out_size, void* d_ws, size_t ws_size,
                              hipStream_t stream) {
    const float* un    = (const float*)d_in[0];
    const float* rgb   = (const float*)d_in[1];
    const int*   spin  = (const int*)  d_in[2];
    const int*   spidx = (const int*)  d_in[3];
    const float* skw   = (const float*)d_in[4];
    const float* bkw   = (const float*)d_in[5];
    const float* lw    = (const float*)d_in[6];
    const float* hwv   = (const float*)d_in[7];
    const float* cm    = (const float*)d_in[8];
    float* out = (float*)d_out;

    float* ws = (float*)d_ws;
    float*    q    = ws;                               // pixel-major f32 (sparse)
    float*    unp  = ws + (size_t)CHW;                 // planar f32
    ushort_t* smb  = (ushort_t*)(ws + (size_t)2*CHW);  // bf16 planar (CHW ushorts)
    ushort_t* pwa  = smb + (size_t)CHW;                // bf16 planar
    ushort_t* pwb  = pwa + (size_t)CHW;                // bf16 planar (dense mode)
    float* guide = ws + (size_t)2*CHW + ((size_t)3*CHW + 1)/2;  // after 3 ushort planes
    float* rsn   = guide + HWN;
    float* rbn   = rsn + HWN;
    int*   spmT  = (int*)(rbn + HWN);
    float* M1t   = rbn + 2*(size_t)HWN;                // after spmT (HWN ints)
    float* M2t   = M1t + CC*CC;
    float* d1    = M2t + CC*CC;
    float* d2    = d1 + CC;
    int*   dflag = (int*)(d2 + CC);
    float* kbuf  = d2 + CC + 4;
    float* sums  = kbuf + 2*KS;                        // NITER * NBKT * 64 floats

    dim3 blk(256);
    int gpix  = HWN / 256;                 // 1024 blocks
    int gpair = HPN / 256;                 // 512 blocks
    dim3 gblur(WW/TW, HH/TH, CC);          // 4 x 32 x 21
    dim3 gnorm(WW/TW, HH/TH, 1);

    k_init_small<<<1, 512, 0, stream>>>(cm, skw, bkw, M1t, M2t, d1, d2, dflag,
                                        kbuf, sums);
    k_init_maps<<<gpix, blk, 0, stream>>>(rgb, spin, un, guide, spmT, unp, smb,
                                          spidx, sums);
    k_norm<<<gnorm, blk, 0, stream>>>(guide, rsn, rbn, kbuf);

    for (int it = 0; it < NITER; ++it) {
        int last = (it == NITER - 1) ? 1 : 0;
        float* su  = sums + it*NBKT*64;
        float* sun = last ? nullptr : (sums + (it+1)*NBKT*64);
        const float* qin = (it == 0) ? un : q;
        k_blur<<<gblur, blk, 0, stream>>>(smb, guide, pwa, pwb, rsn, rbn,
                                          d1, d2, dflag, kbuf);
        k_update<<<gpair, blk, 0, stream>>>(unp, qin, pwa, pwb, M1t, M2t, dflag,
                                            su, sun, lw, hwv,
                                            spmT, spidx, it, q, smb, out, last);
    }
}

// Round 11
// 300.294 us; speedup vs baseline: 2.9654x; 1.3668x over previous
//
#include <hip/hip_runtime.h>
#include <math.h>

#define CC 21
#define HH 512
#define WW 512
#define HWN (HH*WW)
#define HPN (HWN/2)
#define CHW (CC*HWN)
#define RAD 7
#define KS 15
#define NITER 5
#define NBKT 16

#define TW 128
#define TH 16
#define TWH (TW + 2*RAD)   // 142
#define LSTR 145           // odd LDS row stride

#define FEXP(x) __expf(x)
#define FLOG(x) __logf(x)
#define FRCP(x) __builtin_amdgcn_rcpf(x)

// ---------------------------------------------------------------------------
// init: M1t/M2t, diag extracts + flag, taps, zero sums (all parallel)
// ---------------------------------------------------------------------------
__global__ void k_init_small(const float* __restrict__ cm,
                             const float* __restrict__ skw,
                             const float* __restrict__ bkw,
                             float* __restrict__ M1t, float* __restrict__ M2t,
                             float* __restrict__ d1, float* __restrict__ d2,
                             int* __restrict__ dflag,
                             float* __restrict__ kbuf,
                             float* __restrict__ sums) {
    __shared__ int sbad;
    int t = threadIdx.x;
    if (t == 0) sbad = 0;
    __syncthreads();
    if (t < CC*CC) {
        int k = t / CC, c = t % CC;
        float a = 0.f, b = 0.f;
        for (int m = 0; m < CC; ++m) {
            a += cm[c*CC+m] * skw[m*CC+k];
            b += cm[c*CC+m] * bkw[m*CC+k];
        }
        M1t[t] = a; M2t[t] = b;
        if (k != c && (a != 0.f || b != 0.f)) atomicOr(&sbad, 1);
        if (k == c) { d1[c] = a; d2[c] = b; }
    }
    for (int i = t; i < NITER*NBKT*64; i += blockDim.x) sums[i] = 0.f;
    if (t == CC*CC) {
        float w3[KS], w10[KS];
        float s3 = 0.f, s10 = 0.f;
        for (int i = 0; i < KS; ++i) {
            float x = (float)(i - RAD);
            w3[i]  = expf(-0.5f * (x/3.0f)  * (x/3.0f));
            w10[i] = expf(-0.5f * (x/10.0f) * (x/10.0f));
            s3 += w3[i]; s10 += w10[i];
        }
        for (int i = 0; i < KS; ++i) {
            kbuf[i]      = w3[i]  / s3;
            kbuf[KS + i] = w10[i] / s10;
        }
    }
    __syncthreads();
    if (t == 0) dflag[0] = sbad ? 0 : 1;
}

// ---------------------------------------------------------------------------
// guide, spmT, unp (planar f32), sm0 = softmax(un) (f32 planar), clique sums
// for iter 0.  un read coalesced via float4->LDS staging.
// ---------------------------------------------------------------------------
__global__ void __launch_bounds__(256, 4)
k_init_maps(const float* __restrict__ rgb,
            const int* __restrict__ spin,
            const float* __restrict__ un,
            float* __restrict__ guide,
            int* __restrict__ spmT,
            float* __restrict__ unp,
            float* __restrict__ sm,
            const int* __restrict__ spidx,
            float* __restrict__ sums0) {
    __shared__ float lun[256*CC];
    {
        const float4* src = (const float4*)(un + (size_t)blockIdx.x*(256*CC));
        float4* dst = (float4*)lun;
        for (int i = threadIdx.x; i < (256*CC)/4; i += 256) dst[i] = src[i];
    }
    __syncthreads();
    int p = blockIdx.x * blockDim.x + threadIdx.x;
    int h = p / WW, w = p - h*WW;
    float r = rgb[p*3+0] * (1.0f/255.0f);
    float g = rgb[p*3+1] * (1.0f/255.0f);
    float b = rgb[p*3+2] * (1.0f/255.0f);
    guide[p] = FEXP(-0.5f * (r*r + g*g + b*b) / 9.0f);   // theta_beta^2 = 9
    int s = spin[w*HH + h];
    spmT[p] = s;
    int tb = threadIdx.x * CC;
    float v[CC];
    #pragma unroll
    for (int c = 0; c < CC; ++c) { v[c] = lun[tb + c]; unp[c*HWN + p] = v[c]; }
    float mx = v[0];
    #pragma unroll
    for (int c = 1; c < CC; ++c) mx = fmaxf(mx, v[c]);
    float e[CC], ssum = 0.f;
    #pragma unroll
    for (int c = 0; c < CC; ++c) { e[c] = FEXP(v[c] - mx); ssum += e[c]; }
    float inv = FRCP(ssum);
    #pragma unroll
    for (int c = 0; c < CC; ++c) sm[c*HWN + p] = e[c] * inv;

    int sidx = spidx[0];
    bool c1 = (s == sidx), c2 = (s == sidx + 1);
    if (c1 || c2) {
        float* bkt = sums0 + (blockIdx.x & (NBKT-1)) * 64;
        float emx = FEXP(mx);
        if (c1) {
            #pragma unroll
            for (int c = 0; c < CC; ++c) {
                float ev = e[c] * emx;                       // exp(q)
                atomicAdd(&bkt[c], ev - 1.0f);
                float ea = (v[c] == mx) ? emx : ev * emx;    // exp(A_np)
                atomicAdd(&bkt[CC + c], ea - 1.0f);
            }
        } else {
            #pragma unroll
            for (int c = 0; c < CC; ++c) atomicAdd(&bkt[2*CC + c], e[c] * emx - 1.0f);
        }
    }
}

// ---------------------------------------------------------------------------
// norm pass: blur(1) and blur(guide) -> write reciprocal norms (f32).
// ---------------------------------------------------------------------------
__global__ void __launch_bounds__(256, 4)
k_norm(const float* __restrict__ guide,
       float* __restrict__ rsn, float* __restrict__ rbn,
       const float* __restrict__ kbuf) {
    __shared__ float vbs[TH][LSTR];
    __shared__ float vbb[TH][LSTR];
    __shared__ float k3s[KS], k10s[KS];
    int t = threadIdx.x;
    if (t < KS) { k3s[t] = kbuf[t]; k10s[t] = kbuf[KS + t]; }
    __syncthreads();

    int x0 = blockIdx.x * TW;
    int y0 = blockIdx.y * TH;

    for (int u = t; u < 2*TWH; u += 256) {
        int col  = (u < TWH) ? u : u - TWH;
        int half = (u < TWH) ? 0 : 1;
        int xg = x0 - RAD + col;
        bool xok = (xg >= 0 && xg < WW);
        int yb = y0 + half*8;
        float vv[22], gg[22];
        #pragma unroll
        for (int i = 0; i < 22; ++i) {
            int yg = yb - RAD + i;
            bool ok = xok && (yg >= 0) && (yg < HH);
            vv[i] = ok ? 1.0f : 0.f;
            gg[i] = ok ? guide[yg*WW + xg] : 0.f;
        }
        #pragma unroll
        for (int y = 0; y < 8; ++y) {
            float as = 0.f, ab = 0.f;
            #pragma unroll
            for (int d = 0; d < KS; ++d) {
                as += k3s[d]  * vv[y + d];
                ab += k10s[d] * gg[y + d];
            }
            vbs[half*8 + y][col] = as; vbb[half*8 + y][col] = ab;
        }
    }
    __syncthreads();

    int oy = t & 15;
    int xs = (t >> 4) * 8;
    int rowp = (y0 + oy)*WW + x0 + xs;

    float wS[22], wB[22];
    #pragma unroll
    for (int i = 0; i < 22; ++i) { wS[i] = vbs[oy][xs + i]; wB[i] = vbb[oy][xs + i]; }
    #pragma unroll
    for (int j = 0; j < 8; ++j) {
        float a = 0.f, b = 0.f;
        #pragma unroll
        for (int d = 0; d < KS; ++d) { a += k3s[d] * wS[j + d]; b += k10s[d] * wB[j + d]; }
        rsn[rowp + j] = 1.0f / a;
        rbn[rowp + j] = 1.0f / b;
    }
}

// ---------------------------------------------------------------------------
// fused separable blur on f32 sm planes (round-6 proven structure).
// tile 128x16. v-pass: 284 (col, 8-row half) units over 256 threads.
// h-pass: oy=t&15, xs=(t>>4)*8 (2-way LDS banks = free).
// diag -> combined f32 pairwise plane; dense -> two planes.
// ---------------------------------------------------------------------------
__global__ void __launch_bounds__(256, 4)
k_blur(const float* __restrict__ in,
       const float* __restrict__ guide,
       float* __restrict__ outs, float* __restrict__ outb,
       const float* __restrict__ rsn, const float* __restrict__ rbn,
       const float* __restrict__ d1, const float* __restrict__ d2,
       const int* __restrict__ dflag,
       const float* __restrict__ kbuf) {
    __shared__ float vbs[TH][LSTR];
    __shared__ float vbb[TH][LSTR];
    __shared__ float k3s[KS], k10s[KS];
    int t = threadIdx.x;
    if (t < KS) { k3s[t] = kbuf[t]; k10s[t] = kbuf[KS + t]; }
    __syncthreads();

    int c  = blockIdx.z;
    int x0 = blockIdx.x * TW;
    int y0 = blockIdx.y * TH;
    const float* base = in + (size_t)c*HWN;

    for (int u = t; u < 2*TWH; u += 256) {
        int col  = (u < TWH) ? u : u - TWH;
        int half = (u < TWH) ? 0 : 1;
        int xg = x0 - RAD + col;
        bool xok = (xg >= 0 && xg < WW);
        int yb = y0 + half*8;
        float vv[22], gg[22];
        #pragma unroll
        for (int i = 0; i < 22; ++i) {
            int yg = yb - RAD + i;
            bool ok = xok && (yg >= 0) && (yg < HH);
            vv[i] = ok ? base[yg*WW + xg] : 0.f;
            gg[i] = ok ? guide[yg*WW + xg] : 0.f;
        }
        #pragma unroll
        for (int i = 0; i < 22; ++i) gg[i] *= vv[i];
        #pragma unroll
        for (int y = 0; y < 8; ++y) {
            float as = 0.f, ab = 0.f;
            #pragma unroll
            for (int d = 0; d < KS; ++d) {
                as += k3s[d]  * vv[y + d];
                ab += k10s[d] * gg[y + d];
            }
            vbs[half*8 + y][col] = as; vbb[half*8 + y][col] = ab;
        }
    }
    __syncthreads();

    int oy = t & 15;
    int xs = (t >> 4) * 8;
    int gy = y0 + oy;
    int rowp = gy*WW + x0 + xs;
    size_t ob = (size_t)c*HWN + rowp;

    float wS[22], wB[22];
    #pragma unroll
    for (int i = 0; i < 22; ++i) { wS[i] = vbs[oy][xs + i]; wB[i] = vbb[oy][xs + i]; }

    float resS[8], resB[8];
    #pragma unroll
    for (int j = 0; j < 8; ++j) {
        float a = 0.f, b = 0.f;
        #pragma unroll
        for (int d = 0; d < KS; ++d) { a += k3s[d] * wS[j + d]; b += k10s[d] * wB[j + d]; }
        resS[j] = a; resB[j] = b;
    }

    if (dflag[0]) {
        float d1c = d1[c], d2c = d2[c];
        #pragma unroll
        for (int j = 0; j < 8; ++j)
            outs[ob + j] = d1c * resS[j] * rsn[rowp + j]
                         + d2c * resB[j] * rbn[rowp + j];
    } else {
        #pragma unroll
        for (int j = 0; j < 8; ++j) {
            outs[ob + j] = resS[j] * rsn[rowp + j];
            outb[ob + j] = resB[j] * rbn[rowp + j];
        }
    }
}

// ---------------------------------------------------------------------------
// q_{i+1} = u - pairwise - cru(q_i); softmax + clique sums for iter i+1.
// TWO pixels per thread: float2 pw/unp/sm accesses, int2 spmT.
// q pixel-major f32, clique-sparse.
// ---------------------------------------------------------------------------
__global__ void __launch_bounds__(256, 2)
k_update(const float* __restrict__ unp,
         const float* __restrict__ qin,   // pixel-major: un on iter 0, else q
         const float* __restrict__ pw,
         const float* __restrict__ blo,
         const float* __restrict__ M1t,   // [k][c]
         const float* __restrict__ M2t,
         const int* __restrict__ dflag,
         const float* __restrict__ sums_cur,
         float* __restrict__ sums_next,
         const float* __restrict__ lwg,
         const float* __restrict__ hwg,
         const int* __restrict__ spmT,
         const int* __restrict__ spidx, int iter,
         float* __restrict__ q,
         float* __restrict__ sm,
         float* __restrict__ out, int last) {
    __shared__ float slse[3*CC];
    if (threadIdx.x < 3*CC) {
        float s = 0.f;
        #pragma unroll
        for (int b = 0; b < NBKT; ++b) s += sums_cur[b*64 + threadIdx.x];
        slse[threadIdx.x] = FLOG((float)HWN + s);
    }
    __syncthreads();

    int j = blockIdx.x * blockDim.x + threadIdx.x;   // pixel-pair index
    int p0 = 2*j, p1 = p0 + 1;
    int sidx = spidx[iter];
    int2 ss = ((const int2*)spmT)[j];
    const float2* pw2  = (const float2*)pw;
    const float2* blo2 = (const float2*)blo;
    const float2* unp2 = (const float2*)unp;
    float2* sm2 = (float2*)sm;

    float fa1 = (ss.x == sidx)     ? 1.f : 0.f;
    float fa2 = (ss.x == sidx + 1) ? 1.f : 0.f;
    float fb1 = (ss.y == sidx)     ? 1.f : 0.f;
    float fb2 = (ss.y == sidx + 1) ? 1.f : 0.f;

    float acc0[CC], acc1[CC];
    if (dflag[0]) {
        #pragma unroll
        for (int c = 0; c < CC; ++c) {
            float2 w = pw2[c*HPN + j];
            acc0[c] = w.x; acc1[c] = w.y;
        }
    } else {
        #pragma unroll
        for (int c = 0; c < CC; ++c) { acc0[c] = 0.f; acc1[c] = 0.f; }
        for (int k = 0; k < CC; ++k) {
            float2 wp = pw2[k*HPN + j];
            float2 wb = blo2[k*HPN + j];
            #pragma unroll
            for (int c = 0; c < CC; ++c) {
                float m1 = M1t[k*CC + c], m2 = M2t[k*CC + c];
                acc0[c] += m1*wp.x + m2*wb.x;
                acc1[c] += m1*wp.y + m2*wb.y;
            }
        }
    }

    float hw0 = hwg[0], hw1 = hwg[1], hw2 = hwg[2];
    bool any_clique = __any(fa1 + fa2 + fb1 + fb2 != 0.f);
    if (any_clique) {
        float v0[CC], v1[CC];
        #pragma unroll
        for (int c = 0; c < CC; ++c) { v0[c] = qin[p0*CC + c]; v1[c] = qin[p1*CC + c]; }
        float mx0 = v0[0], mx1 = v1[0];
        #pragma unroll
        for (int c = 1; c < CC; ++c) { mx0 = fmaxf(mx0, v0[c]); mx1 = fmaxf(mx1, v1[c]); }
        #pragma unroll
        for (int c = 0; c < CC; ++c) {
            float2 uu = unp2[c*HPN + j];
            {
                float qv = v0[c];
                float qmod = qv + ((qv == 0.f) ? 1.f : 0.f);
                float anp = fa1 * (qv + mx0) - ((fa1 != 0.f && qv == mx0) ? qv : 0.f);
                float qst = anp + ((anp == 0.f) ? 1.f : 0.f);
                float p1v = fa1 * slse[c];
                float p2v = fa1 * slse[CC + c];
                float p3v = p1v + fa2 * slse[2*CC + c];
                float ft1 = p1v * FRCP(qmod);
                float ft2 = p2v * FRCP(qst);
                float ft3 = p3v * FRCP(qmod);
                float cru = lwg[c]*ft1        + hw0*(1.f - ft1)
                          + lwg[CC + c]*ft2   + hw1*(1.f - ft2)
                          + lwg[2*CC + c]*ft3 + hw2*(1.f - ft3);
                acc0[c] = uu.x - acc0[c] - cru;
            }
            {
                float qv = v1[c];
                float qmod = qv + ((qv == 0.f) ? 1.f : 0.f);
                float anp = fb1 * (qv + mx1) - ((fb1 != 0.f && qv == mx1) ? qv : 0.f);
                float qst = anp + ((anp == 0.f) ? 1.f : 0.f);
                float p1v = fb1 * slse[c];
                float p2v = fb1 * slse[CC + c];
                float p3v = p1v + fb2 * slse[2*CC + c];
                float ft1 = p1v * FRCP(qmod);
                float ft2 = p2v * FRCP(qst);
                float ft3 = p3v * FRCP(qmod);
                float cru = lwg[c]*ft1        + hw0*(1.f - ft1)
                          + lwg[CC + c]*ft2   + hw1*(1.f - ft2)
                          + lwg[2*CC + c]*ft3 + hw2*(1.f - ft3);
                acc1[c] = uu.y - acc1[c] - cru;
            }
        }
    } else {
        float cruc = hw0 + hw1 + hw2;   // all ft == 0
        #pragma unroll
        for (int c = 0; c < CC; ++c) {
            float2 uu = unp2[c*HPN + j];
            acc0[c] = uu.x - acc0[c] - cruc;
            acc1[c] = uu.y - acc1[c] - cruc;
        }
    }

    if (!last) {
        int sidx2 = spidx[iter + 1];
        bool c1a = (ss.x == sidx2), c2a = (ss.x == sidx2 + 1);
        bool c1b = (ss.y == sidx2), c2b = (ss.y == sidx2 + 1);
        if (c1a || c2a) {
            #pragma unroll
            for (int c = 0; c < CC; ++c) q[p0*CC + c] = acc0[c];
        }
        if (c1b || c2b) {
            #pragma unroll
            for (int c = 0; c < CC; ++c) q[p1*CC + c] = acc1[c];
        }
        float mx0 = acc0[0], mx1 = acc1[0];
        #pragma unroll
        for (int c = 1; c < CC; ++c) { mx0 = fmaxf(mx0, acc0[c]); mx1 = fmaxf(mx1, acc1[c]); }
        float e0[CC], e1[CC], s0 = 0.f, s1 = 0.f;
        #pragma unroll
        for (int c = 0; c < CC; ++c) {
            e0[c] = FEXP(acc0[c] - mx0); s0 += e0[c];
            e1[c] = FEXP(acc1[c] - mx1); s1 += e1[c];
        }
        float i0 = FRCP(s0), i1 = FRCP(s1);
        #pragma unroll
        for (int c = 0; c < CC; ++c) {
            float2 o; o.x = e0[c] * i0; o.y = e1[c] * i1;
            sm2[c*HPN + j] = o;
        }

        if (c1a || c2a) {
            float* bkt = sums_next + (blockIdx.x & (NBKT-1)) * 64;
            float emx = FEXP(mx0);
            if (c1a) {
                #pragma unroll
                for (int c = 0; c < CC; ++c) {
                    float ev = e0[c] * emx;
                    atomicAdd(&bkt[c], ev - 1.0f);
                    float ea = (acc0[c] == mx0) ? emx : ev * emx;
                    atomicAdd(&bkt[CC + c], ea - 1.0f);
                }
            } else {
                #pragma unroll
                for (int c = 0; c < CC; ++c) atomicAdd(&bkt[2*CC + c], e0[c] * emx - 1.0f);
            }
        }
        if (c1b || c2b) {
            float* bkt = sums_next + (blockIdx.x & (NBKT-1)) * 64;
            float emx = FEXP(mx1);
            if (c1b) {
                #pragma unroll
                for (int c = 0; c < CC; ++c) {
                    float ev = e1[c] * emx;
                    atomicAdd(&bkt[c], ev - 1.0f);
                    float ea = (acc1[c] == mx1) ? emx : ev * emx;
                    atomicAdd(&bkt[CC + c], ea - 1.0f);
                }
            } else {
                #pragma unroll
                for (int c = 0; c < CC; ++c) atomicAdd(&bkt[2*CC + c], e1[c] * emx - 1.0f);
            }
        }
    } else {
        #pragma unroll
        for (int c = 0; c < CC; ++c) {
            out[p0*CC + c] = acc0[c];
            out[p1*CC + c] = acc1[c];
        }
    }
}

// ---------------------------------------------------------------------------
extern "C" void kernel_launch(void* const* d_in, const int* in_sizes, int n_in,
                              void* d_out, int out_size, void* d_ws, size_t ws_size,
                              hipStream_t stream) {
    const float* un    = (const float*)d_in[0];
    const float* rgb   = (const float*)d_in[1];
    const int*   spin  = (const int*)  d_in[2];
    const int*   spidx = (const int*)  d_in[3];
    const float* skw   = (const float*)d_in[4];
    const float* bkw   = (const float*)d_in[5];
    const float* lw    = (const float*)d_in[6];
    const float* hwv   = (const float*)d_in[7];
    const float* cm    = (const float*)d_in[8];
    float* out = (float*)d_out;

    float* ws = (float*)d_ws;
    float* q     = ws;                     // pixel-major f32 (clique-sparse)
    float* unp   = ws + (size_t)CHW;       // planar f32
    float* sm    = ws + (size_t)2*CHW;     // planar f32
    float* pwa   = ws + (size_t)3*CHW;     // planar f32 (combined pw / spatial)
    float* pwb   = ws + (size_t)4*CHW;     // planar f32 (bilateral, dense mode)
    float* guide = ws + (size_t)5*CHW;
    float* rsn   = guide + HWN;
    float* rbn   = rsn + HWN;
    int*   spmT  = (int*)(rbn + HWN);
    float* M1t   = rbn + 2*(size_t)HWN;    // after spmT (HWN ints)
    float* M2t   = M1t + CC*CC;
    float* d1    = M2t + CC*CC;
    float* d2    = d1 + CC;
    int*   dflag = (int*)(d2 + CC);
    float* kbuf  = d2 + CC + 4;
    float* sums  = kbuf + 2*KS;            // NITER * NBKT * 64 floats

    dim3 blk(256);
    int gpix  = HWN / 256;                 // 1024 blocks
    int gpair = HPN / 256;                 // 512 blocks
    dim3 gblur(WW/TW, HH/TH, CC);          // 4 x 32 x 21
    dim3 gnorm(WW/TW, HH/TH, 1);

    k_init_small<<<1, 512, 0, stream>>>(cm, skw, bkw, M1t, M2t, d1, d2, dflag,
                                        kbuf, sums);
    k_init_maps<<<gpix, blk, 0, stream>>>(rgb, spin, un, guide, spmT, unp, sm,
                                          spidx, sums);
    k_norm<<<gnorm, blk, 0, stream>>>(guide, rsn, rbn, kbuf);

    for (int it = 0; it < NITER; ++it) {
        int last = (it == NITER - 1) ? 1 : 0;
        float* su  = sums + it*NBKT*64;
        float* sun = last ? nullptr : (sums + (it+1)*NBKT*64);
        const float* qin = (it == 0) ? un : q;
        k_blur<<<gblur, blk, 0, stream>>>(sm, guide, pwa, pwb, rsn, rbn,
                                          d1, d2, dflag, kbuf);
        k_update<<<gpair, blk, 0, stream>>>(unp, qin, pwa, pwb, M1t, M2t, dflag,
                                            su, sun, lw, hwv,
                                            spmT, spidx, it, q, sm, out, last);
    }
}